// Round 1
// baseline (735.657 us; speedup 1.0000x reference)
//
#include <hip/hip_runtime.h>

// Volume renderer (NeRF-style) — THREAD-per-ray, LDS-tiled.
//
// Structure change vs previous (wave-per-ray) kernel:
//   - 1 thread owns 1 ray and runs the transmittance recurrence serially:
//       e = exp(-sigma*delta);  w = T - T*e;  T *= e;
//     This is exactly the reference cumprod order (better numerics than the
//     exp-of-prefix-sum scan) and needs NO cross-lane ops at all:
//     no wave scan, no 18-shuffle RGB reduction, no sentinel-exclusion hack
//     (exp(-1e10*sigma) underflows to 0 naturally).
//   - 262144 waves -> 4096 waves. Wave-instruction count per byte drops ~7x;
//     the kernel becomes purely HBM-bound.
//   - Global loads are fully-coalesced float4 into LDS tiles
//     (64 rays x 8 samples). LDS rows are padded to an ODD number of
//     float4s (3 / 3 / 7) so per-thread ds_read_b128 of a row is
//     bank-conflict-free ((stride/16B) odd => distinct bank quads).
//   - Block = 64 threads = 1 wave: tile barriers are wave-level (near-free).
//   - dist tile-boundary sample (s0+8) is carried in a register via one
//     scalar load per tile (L2-resident; becomes next tile's staged line).
//
// LDS: 13312 B/block -> 12 blocks/CU. ~13 outstanding dwordx4 per wave
// x 12 waves/CU ≈ 130 KB in flight >> BW*latency (~9 KB) => saturates HBM.

#define FAR_DELTA 1e10f

__global__ __launch_bounds__(64) void volrender_kernel(
    const float* __restrict__ rgb,       // [N, 128, 3]
    const float* __restrict__ density,   // [N, 128, 1]
    const float* __restrict__ dist,      // [N, 128]
    float* __restrict__ out,             // [N, 3]
    int n_rays)
{
    const int t  = threadIdx.x;          // 0..63 — one wave per block
    const int r0 = blockIdx.x << 6;      // 64 rays per block

    // rows padded to odd float4 counts: 12, 12, 28 floats
    __shared__ float SIG[64 * 12];       // density tile (8 floats used/row)
    __shared__ float DST[64 * 12];       // dist tile    (8 floats used/row)
    __shared__ float RGBT[64 * 28];      // rgb tile     (24 floats used/row)

    const int    ray  = min(r0 + t, n_rays - 1);
    const size_t rowD = (size_t)ray * 128;

    float T    = 1.0f;
    float accR = 0.0f, accG = 0.0f, accB = 0.0f;

    for (int tile = 0; tile < 16; ++tile) {
        const int s0 = tile << 3;        // first sample of this tile

        // ---- stage density + dist: 64 rays x 8 samples = 128 float4 each ----
        // j = t + 64k walks float4s linearly => consecutive lanes read
        // consecutive 16B chunks (64B per ray-row, fully-used cache lines).
        #pragma unroll
        for (int k = 0; k < 2; ++k) {
            const int    j   = t + (k << 6);
            const int    row = j >> 1;
            const int    col = (j & 1) << 2;              // 0 or 4 floats
            const int    gr  = min(r0 + row, n_rays - 1);
            const size_t g   = (size_t)gr * 128 + s0 + col;
            const float4 sv  = *(const float4*)(density + g);
            const float4 dv  = *(const float4*)(dist + g);
            *(float4*)(&SIG[row * 12 + col]) = sv;
            *(float4*)(&DST[row * 12 + col]) = dv;
        }
        // ---- stage rgb: 64 rays x 24 floats = 384 float4 ----
        #pragma unroll
        for (int k = 0; k < 6; ++k) {
            const int    j   = t + (k << 6);
            const int    row = j / 6;                     // magic-mul
            const int    col = (j - row * 6) << 2;        // 0,4,...,20 floats
            const int    gr  = min(r0 + row, n_rays - 1);
            const size_t g   = (size_t)gr * 384 + (size_t)s0 * 3 + col;
            *(float4*)(&RGBT[row * 28 + col]) = *(const float4*)(rgb + g);
        }
        // register carry: first dist sample of the NEXT tile (own ray).
        // Value is unused for global sample 127 (sentinel path), so the
        // clamp is only there to keep the address in-bounds.
        const float d_carry = dist[rowD + min(s0 + 8, 127)];

        __syncthreads();   // single-wave block: wave-level sync, near-free

        // ---- compute: this thread's ray, 8 samples, serial recurrence ----
        const float4 sg0 = *(const float4*)(&SIG[t * 12]);
        const float4 sg1 = *(const float4*)(&SIG[t * 12 + 4]);
        const float4 dv0 = *(const float4*)(&DST[t * 12]);
        const float4 dv1 = *(const float4*)(&DST[t * 12 + 4]);

        float cf[24];
        #pragma unroll
        for (int k = 0; k < 6; ++k) {
            const float4 v = *(const float4*)(&RGBT[t * 28 + (k << 2)]);
            cf[(k << 2) + 0] = v.x;  cf[(k << 2) + 1] = v.y;
            cf[(k << 2) + 2] = v.z;  cf[(k << 2) + 3] = v.w;
        }

        const float dl[9] = {dv0.x, dv0.y, dv0.z, dv0.w,
                             dv1.x, dv1.y, dv1.z, dv1.w, d_carry};
        const float sl[8] = {sg0.x, sg0.y, sg0.z, sg0.w,
                             sg1.x, sg1.y, sg1.z, sg1.w};

        #pragma unroll
        for (int j = 0; j < 8; ++j) {
            const float delta = (s0 + j == 127) ? FAR_DELTA : (dl[j + 1] - dl[j]);
            const float e = __expf(-sl[j] * delta);   // lane 127: -> 0 naturally
            const float w = T - T * e;                // alpha_i * T_i
            T *= e;
            accR += w * cf[3 * j + 0];
            accG += w * cf[3 * j + 1];
            accB += w * cf[3 * j + 2];
        }

        __syncthreads();   // WAR: next tile's writes must not pass these reads
    }

    if (r0 + t < n_rays) {
        float* o = out + (size_t)(r0 + t) * 3;
        o[0] = accR;
        o[1] = accG;
        o[2] = accB;
    }
}

extern "C" void kernel_launch(void* const* d_in, const int* in_sizes, int n_in,
                              void* d_out, int out_size, void* d_ws, size_t ws_size,
                              hipStream_t stream) {
    const float* rgb     = (const float*)d_in[0];
    const float* density = (const float*)d_in[1];
    const float* dist    = (const float*)d_in[2];
    float* out = (float*)d_out;

    const int n_rays = in_sizes[2] / 128;   // distances is [N, 128]

    // one 64-thread (single-wave) block per 64 rays
    const int block = 64;
    const int grid  = (n_rays + 63) / 64;

    volrender_kernel<<<grid, block, 0, stream>>>(rgb, density, dist, out, n_rays);
}